// Round 1
// baseline (620.653 us; speedup 1.0000x reference)
//
#include <hip/hip_runtime.h>
#include <hip/hip_bf16.h>

#define D 128
#define KT 32
#define TILE_ROWS 64

// ---------------------------------------------------------------- degree count
__global__ void count_kernel(const int* __restrict__ dst, int* __restrict__ cnt, int E_) {
    int e = blockIdx.x * blockDim.x + threadIdx.x;
    if (e < E_) atomicAdd(&cnt[dst[e]], 1);
}

// ---------------------------------------------------------------- block scan (exclusive within block) + block sums
__global__ __launch_bounds__(256) void scan1_kernel(const int* __restrict__ cnt,
                                                    int* __restrict__ offs,
                                                    int* __restrict__ bsum, int n) {
    __shared__ int s[256];
    int i = blockIdx.x * 256 + threadIdx.x;
    int v = (i < n) ? cnt[i] : 0;
    s[threadIdx.x] = v;
    __syncthreads();
    #pragma unroll
    for (int off = 1; off < 256; off <<= 1) {
        int x = (threadIdx.x >= off) ? s[threadIdx.x - off] : 0;
        __syncthreads();
        s[threadIdx.x] += x;
        __syncthreads();
    }
    if (i < n) offs[i] = s[threadIdx.x] - v;           // exclusive scan within block
    if (threadIdx.x == 255) bsum[blockIdx.x] = s[255]; // block total
}

// ---------------------------------------------------------------- scan of block sums (nb <= 256), in place -> exclusive
__global__ __launch_bounds__(256) void scan2_kernel(int* __restrict__ bsum, int nb) {
    __shared__ int s[256];
    int v = (threadIdx.x < nb) ? bsum[threadIdx.x] : 0;
    s[threadIdx.x] = v;
    __syncthreads();
    #pragma unroll
    for (int off = 1; off < 256; off <<= 1) {
        int x = (threadIdx.x >= off) ? s[threadIdx.x - off] : 0;
        __syncthreads();
        s[threadIdx.x] += x;
        __syncthreads();
    }
    if (threadIdx.x < nb) bsum[threadIdx.x] = s[threadIdx.x] - v; // exclusive
}

// ---------------------------------------------------------------- add block offsets, init cursor, dinv
__global__ void finalize_kernel(const int* __restrict__ cnt, int* __restrict__ offs,
                                int* __restrict__ cursor, float* __restrict__ dinv,
                                const int* __restrict__ bsum, int n, int Etot) {
    int i = blockIdx.x * 256 + threadIdx.x;
    if (i < n) {
        int off = offs[i] + bsum[blockIdx.x];
        offs[i]   = off;
        cursor[i] = off;
        dinv[i]   = rsqrtf((float)(cnt[i] + 1)); // +1 self-loop; deg >= 1 always
    }
    if (i == 0) offs[n] = Etot;
}

// ---------------------------------------------------------------- CSR fill (counting sort by dst)
__global__ void fill_kernel(const int* __restrict__ src, const int* __restrict__ dst,
                            int* __restrict__ cursor, int* __restrict__ col, int E_) {
    int e = blockIdx.x * blockDim.x + threadIdx.x;
    if (e < E_) {
        int d   = dst[e];
        int pos = atomicAdd(&cursor[d], 1);
        col[pos] = src[e];
    }
}

// ---------------------------------------------------------------- G = (A @ W) * dinv[row]   (fp32, vector ALU)
// 64-row x 128-col tile per block; 256 threads; each thread 8 rows x 4 cols.
__global__ __launch_bounds__(256) void gemm_scale_kernel(const float* __restrict__ A,
                                                         const float* __restrict__ W,
                                                         const float* __restrict__ dinv,
                                                         float* __restrict__ G, int nrows) {
    __shared__ float As[TILE_ROWS][KT + 4]; // stride 36 floats = 144 B (16B-aligned for b128)
    __shared__ float Ws[KT][D];

    const int tid = threadIdx.x;
    const int tc  = tid & 31;  // col group -> cols 4*tc .. 4*tc+3
    const int tr  = tid >> 5;  // row group 0..7 -> rows tr*8 .. tr*8+7
    const int row0 = blockIdx.x * TILE_ROWS;

    float acc[8][4];
    #pragma unroll
    for (int r = 0; r < 8; ++r)
        #pragma unroll
        for (int c = 0; c < 4; ++c) acc[r][c] = 0.f;

    for (int kc = 0; kc < D; kc += KT) {
        // stage A chunk: 64 rows x 32 k = 512 float4; 2 per thread
        #pragma unroll
        for (int l = 0; l < 2; ++l) {
            int li = tid + l * 256;
            int r  = li >> 3;
            int k4 = li & 7;
            int grow = row0 + r;
            float4 v = make_float4(0.f, 0.f, 0.f, 0.f);
            if (grow < nrows) v = *(const float4*)&A[grow * D + kc + 4 * k4];
            *(float4*)&As[r][4 * k4] = v;
        }
        // stage W chunk: 32 k x 128 cols = 1024 float4; 4 per thread
        #pragma unroll
        for (int l = 0; l < 4; ++l) {
            int li = tid + l * 256;
            int k  = li >> 5;
            int c4 = li & 31;
            *(float4*)&Ws[k][4 * c4] = *(const float4*)&W[(kc + k) * D + 4 * c4];
        }
        __syncthreads();

        #pragma unroll
        for (int k4 = 0; k4 < KT / 4; ++k4) {
            float4 w0 = *(float4*)&Ws[4 * k4 + 0][4 * tc];
            float4 w1 = *(float4*)&Ws[4 * k4 + 1][4 * tc];
            float4 w2 = *(float4*)&Ws[4 * k4 + 2][4 * tc];
            float4 w3 = *(float4*)&Ws[4 * k4 + 3][4 * tc];
            #pragma unroll
            for (int r = 0; r < 8; ++r) {
                float4 a = *(float4*)&As[tr * 8 + r][4 * k4];
                acc[r][0] += a.x * w0.x + a.y * w1.x + a.z * w2.x + a.w * w3.x;
                acc[r][1] += a.x * w0.y + a.y * w1.y + a.z * w2.y + a.w * w3.y;
                acc[r][2] += a.x * w0.z + a.y * w1.z + a.z * w2.z + a.w * w3.z;
                acc[r][3] += a.x * w0.w + a.y * w1.w + a.z * w2.w + a.w * w3.w;
            }
        }
        __syncthreads();
    }

    #pragma unroll
    for (int r = 0; r < 8; ++r) {
        int grow = row0 + tr * 8 + r;
        if (grow < nrows) {
            float s = dinv[grow];
            float4 o = make_float4(acc[r][0] * s, acc[r][1] * s, acc[r][2] * s, acc[r][3] * s);
            *(float4*)&G[grow * D + 4 * tc] = o;
        }
    }
}

// ---------------------------------------------------------------- out[i] = relu(dinv[i]*(sum_{j in N(i)} g[j] + g[i]) + b)
// One 32-thread group per node (float4/lane), 8 nodes per 256-block.
__global__ __launch_bounds__(256) void aggregate_kernel(const float* __restrict__ G,
                                                        const int* __restrict__ offs,
                                                        const int* __restrict__ col,
                                                        const float* __restrict__ dinv,
                                                        const float* __restrict__ bias,
                                                        float* __restrict__ out, int nnodes) {
    const int lane = threadIdx.x & 31;
    const int node = blockIdx.x * 8 + (threadIdx.x >> 5);
    if (node >= nnodes) return;
    const int c = lane * 4;

    float4 acc = *(const float4*)&G[node * D + c]; // self-loop term (g_i)
    int s = offs[node];
    int e = offs[node + 1];

    int idx = s;
    for (; idx + 4 <= e; idx += 4) {
        int j0 = col[idx + 0], j1 = col[idx + 1], j2 = col[idx + 2], j3 = col[idx + 3];
        float4 v0 = *(const float4*)&G[j0 * D + c];
        float4 v1 = *(const float4*)&G[j1 * D + c];
        float4 v2 = *(const float4*)&G[j2 * D + c];
        float4 v3 = *(const float4*)&G[j3 * D + c];
        acc.x += (v0.x + v1.x) + (v2.x + v3.x);
        acc.y += (v0.y + v1.y) + (v2.y + v3.y);
        acc.z += (v0.z + v1.z) + (v2.z + v3.z);
        acc.w += (v0.w + v1.w) + (v2.w + v3.w);
    }
    for (; idx < e; ++idx) {
        int j = col[idx];
        float4 v = *(const float4*)&G[j * D + c];
        acc.x += v.x; acc.y += v.y; acc.z += v.z; acc.w += v.w;
    }

    float dv = dinv[node];
    float4 b = *(const float4*)&bias[c];
    float4 o;
    o.x = fmaxf(fmaf(dv, acc.x, b.x), 0.f);
    o.y = fmaxf(fmaf(dv, acc.y, b.y), 0.f);
    o.z = fmaxf(fmaf(dv, acc.z, b.z), 0.f);
    o.w = fmaxf(fmaf(dv, acc.w, b.w), 0.f);
    *(float4*)&out[node * D + c] = o;
}

// ----------------------------------------------------------------
extern "C" void kernel_launch(void* const* d_in, const int* in_sizes, int n_in,
                              void* d_out, int out_size, void* d_ws, size_t ws_size,
                              hipStream_t stream) {
    const float* x    = (const float*)d_in[0];
    const int*   edge = (const int*)d_in[1];
    const float* W0   = (const float*)d_in[2];
    const float* b0   = (const float*)d_in[3];
    const float* W1   = (const float*)d_in[4];
    const float* b1   = (const float*)d_in[5];
    float* out = (float*)d_out;

    const int N_ = in_sizes[0] / D;
    const int E_ = in_sizes[1] / 2;
    const int* srcp = edge;       // edge_index[0]
    const int* dstp = edge + E_;  // edge_index[1]

    // workspace carve (256B-aligned chunks)
    char* p = (char*)d_ws;
    auto carve = [&](size_t bytes) { char* q = p; p += (bytes + 255) & ~(size_t)255; return q; };
    int*   cnt    = (int*)  carve((size_t)N_ * 4);
    int*   offs   = (int*)  carve((size_t)(N_ + 1) * 4);
    int*   cursor = (int*)  carve((size_t)N_ * 4);
    int*   bsum   = (int*)  carve(1024);
    float* dinv   = (float*)carve((size_t)N_ * 4);
    int*   col    = (int*)  carve((size_t)E_ * 4);
    float* g      = (float*)carve((size_t)N_ * D * 4);

    hipMemsetAsync(cnt, 0, (size_t)N_ * 4, stream);

    const int eb = (E_ + 255) / 256;
    const int nb = (N_ + 255) / 256;  // 196 for N=50000 (<=256 required by scan2)

    count_kernel<<<eb, 256, 0, stream>>>(dstp, cnt, E_);
    scan1_kernel<<<nb, 256, 0, stream>>>(cnt, offs, bsum, N_);
    scan2_kernel<<<1, 256, 0, stream>>>(bsum, nb);
    finalize_kernel<<<nb, 256, 0, stream>>>(cnt, offs, cursor, dinv, bsum, N_, E_);
    fill_kernel<<<eb, 256, 0, stream>>>(srcp, dstp, cursor, col, E_);

    const int gb = (N_ + TILE_ROWS - 1) / TILE_ROWS;
    const int ab = (N_ + 7) / 8;

    // layer 1: g = (x@W0)*dinv ; out(d_out as scratch) = relu(dinv*(agg+g)+b0)
    gemm_scale_kernel<<<gb, 256, 0, stream>>>(x, W0, dinv, g, N_);
    aggregate_kernel<<<ab, 256, 0, stream>>>(g, offs, col, dinv, b0, out, N_);
    // layer 2: g = (out@W1)*dinv ; out = relu(dinv*(agg+g)+b1)
    gemm_scale_kernel<<<gb, 256, 0, stream>>>(out, W1, dinv, g, N_);
    aggregate_kernel<<<ab, 256, 0, stream>>>(g, offs, col, dinv, b1, out, N_);
}

// Round 2
// 563.629 us; speedup vs baseline: 1.1012x; 1.1012x over previous
//
#include <hip/hip_runtime.h>
#include <hip/hip_bf16.h>

#define D 128
#define KT 32
#define TILE_ROWS 64

// ---------------------------------------------------------------- count + rank (vectorized)
// rank[e] = number of earlier-processed edges with same dst (any order is a valid rank).
__global__ __launch_bounds__(256) void count_rank_vec(const int* __restrict__ dst,
                                                      int* __restrict__ cnt,
                                                      int* __restrict__ rank,
                                                      int n4, int E_) {
    int i = blockIdx.x * 256 + threadIdx.x;
    if (i < n4) {
        int4 d = ((const int4*)dst)[i];
        int4 r;
        r.x = atomicAdd(&cnt[d.x], 1);
        r.y = atomicAdd(&cnt[d.y], 1);
        r.z = atomicAdd(&cnt[d.z], 1);
        r.w = atomicAdd(&cnt[d.w], 1);
        ((int4*)rank)[i] = r;
    }
    if (i == 0) { // tail (E_ % 4)
        for (int e = n4 * 4; e < E_; ++e) rank[e] = atomicAdd(&cnt[dst[e]], 1);
    }
}

// scalar fallback (only if edge pointers not int4-aligned)
__global__ void count_rank_scalar(const int* __restrict__ dst, int* __restrict__ cnt,
                                  int* __restrict__ rank, int E_) {
    int e = blockIdx.x * blockDim.x + threadIdx.x;
    if (e < E_) rank[e] = atomicAdd(&cnt[dst[e]], 1);
}

// ---------------------------------------------------------------- block scan (exclusive within block) + block sums
__global__ __launch_bounds__(256) void scan1_kernel(const int* __restrict__ cnt,
                                                    int* __restrict__ offs,
                                                    int* __restrict__ bsum, int n) {
    __shared__ int s[256];
    int i = blockIdx.x * 256 + threadIdx.x;
    int v = (i < n) ? cnt[i] : 0;
    s[threadIdx.x] = v;
    __syncthreads();
    #pragma unroll
    for (int off = 1; off < 256; off <<= 1) {
        int x = (threadIdx.x >= off) ? s[threadIdx.x - off] : 0;
        __syncthreads();
        s[threadIdx.x] += x;
        __syncthreads();
    }
    if (i < n) offs[i] = s[threadIdx.x] - v;
    if (threadIdx.x == 255) bsum[blockIdx.x] = s[255];
}

// ---------------------------------------------------------------- scan of block sums (nb <= 256)
__global__ __launch_bounds__(256) void scan2_kernel(int* __restrict__ bsum, int nb) {
    __shared__ int s[256];
    int v = (threadIdx.x < nb) ? bsum[threadIdx.x] : 0;
    s[threadIdx.x] = v;
    __syncthreads();
    #pragma unroll
    for (int off = 1; off < 256; off <<= 1) {
        int x = (threadIdx.x >= off) ? s[threadIdx.x - off] : 0;
        __syncthreads();
        s[threadIdx.x] += x;
        __syncthreads();
    }
    if (threadIdx.x < nb) bsum[threadIdx.x] = s[threadIdx.x] - v;
}

// ---------------------------------------------------------------- add block offsets, dinv
__global__ void finalize_kernel(const int* __restrict__ cnt, int* __restrict__ offs,
                                float* __restrict__ dinv,
                                const int* __restrict__ bsum, int n, int Etot) {
    int i = blockIdx.x * 256 + threadIdx.x;
    if (i < n) {
        offs[i] = offs[i] + bsum[blockIdx.x];
        dinv[i] = rsqrtf((float)(cnt[i] + 1)); // +1 self-loop
    }
    if (i == 0) offs[n] = Etot;
}

// ---------------------------------------------------------------- CSR fill
// atomicExch (no return) executes at the device coherence point (MALL) instead of
// migrating dirty-exclusive lines through per-XCD L2 -> kills the 101MB parasitic
// HBM write traffic the plain scattered stores caused (R1 counters).
__global__ __launch_bounds__(256) void fill_vec(const int* __restrict__ src,
                                                const int* __restrict__ dst,
                                                const int* __restrict__ rank,
                                                const int* __restrict__ offs,
                                                int* __restrict__ col, int n4, int E_) {
    int i = blockIdx.x * 256 + threadIdx.x;
    if (i < n4) {
        int4 d = ((const int4*)dst)[i];
        int4 s = ((const int4*)src)[i];
        int4 r = ((const int4*)rank)[i];
        atomicExch(&col[offs[d.x] + r.x], s.x);
        atomicExch(&col[offs[d.y] + r.y], s.y);
        atomicExch(&col[offs[d.z] + r.z], s.z);
        atomicExch(&col[offs[d.w] + r.w], s.w);
    }
    if (i == 0) { // tail
        for (int e = n4 * 4; e < E_; ++e)
            atomicExch(&col[offs[dst[e]] + rank[e]], src[e]);
    }
}

__global__ void fill_scalar(const int* __restrict__ src, const int* __restrict__ dst,
                            const int* __restrict__ rank, const int* __restrict__ offs,
                            int* __restrict__ col, int E_) {
    int e = blockIdx.x * blockDim.x + threadIdx.x;
    if (e < E_) atomicExch(&col[offs[dst[e]] + rank[e]], src[e]);
}

// ---------------------------------------------------------------- G = (A @ W) * dinv[row]   (fp32, vector ALU)
__global__ __launch_bounds__(256) void gemm_scale_kernel(const float* __restrict__ A,
                                                         const float* __restrict__ W,
                                                         const float* __restrict__ dinv,
                                                         float* __restrict__ G, int nrows) {
    __shared__ float As[TILE_ROWS][KT + 4];
    __shared__ float Ws[KT][D];

    const int tid = threadIdx.x;
    const int tc  = tid & 31;
    const int tr  = tid >> 5;
    const int row0 = blockIdx.x * TILE_ROWS;

    float acc[8][4];
    #pragma unroll
    for (int r = 0; r < 8; ++r)
        #pragma unroll
        for (int c = 0; c < 4; ++c) acc[r][c] = 0.f;

    for (int kc = 0; kc < D; kc += KT) {
        #pragma unroll
        for (int l = 0; l < 2; ++l) {
            int li = tid + l * 256;
            int r  = li >> 3;
            int k4 = li & 7;
            int grow = row0 + r;
            float4 v = make_float4(0.f, 0.f, 0.f, 0.f);
            if (grow < nrows) v = *(const float4*)&A[grow * D + kc + 4 * k4];
            *(float4*)&As[r][4 * k4] = v;
        }
        #pragma unroll
        for (int l = 0; l < 4; ++l) {
            int li = tid + l * 256;
            int k  = li >> 5;
            int c4 = li & 31;
            *(float4*)&Ws[k][4 * c4] = *(const float4*)&W[(kc + k) * D + 4 * c4];
        }
        __syncthreads();

        #pragma unroll
        for (int k4 = 0; k4 < KT / 4; ++k4) {
            float4 w0 = *(float4*)&Ws[4 * k4 + 0][4 * tc];
            float4 w1 = *(float4*)&Ws[4 * k4 + 1][4 * tc];
            float4 w2 = *(float4*)&Ws[4 * k4 + 2][4 * tc];
            float4 w3 = *(float4*)&Ws[4 * k4 + 3][4 * tc];
            #pragma unroll
            for (int r = 0; r < 8; ++r) {
                float4 a = *(float4*)&As[tr * 8 + r][4 * k4];
                acc[r][0] += a.x * w0.x + a.y * w1.x + a.z * w2.x + a.w * w3.x;
                acc[r][1] += a.x * w0.y + a.y * w1.y + a.z * w2.y + a.w * w3.y;
                acc[r][2] += a.x * w0.z + a.y * w1.z + a.z * w2.z + a.w * w3.z;
                acc[r][3] += a.x * w0.w + a.y * w1.w + a.z * w2.w + a.w * w3.w;
            }
        }
        __syncthreads();
    }

    #pragma unroll
    for (int r = 0; r < 8; ++r) {
        int grow = row0 + tr * 8 + r;
        if (grow < nrows) {
            float s = dinv[grow];
            float4 o = make_float4(acc[r][0] * s, acc[r][1] * s, acc[r][2] * s, acc[r][3] * s);
            *(float4*)&G[grow * D + 4 * tc] = o;
        }
    }
}

// ---------------------------------------------------------------- out[i] = relu(dinv[i]*(sum_j g[j] + g[i]) + b)
__global__ __launch_bounds__(256) void aggregate_kernel(const float* __restrict__ G,
                                                        const int* __restrict__ offs,
                                                        const int* __restrict__ col,
                                                        const float* __restrict__ dinv,
                                                        const float* __restrict__ bias,
                                                        float* __restrict__ out, int nnodes) {
    const int lane = threadIdx.x & 31;
    const int node = blockIdx.x * 8 + (threadIdx.x >> 5);
    if (node >= nnodes) return;
    const int c = lane * 4;

    float4 acc = *(const float4*)&G[node * D + c]; // self-loop
    int s = offs[node];
    int e = offs[node + 1];

    int idx = s;
    for (; idx + 8 <= e; idx += 8) {
        int j0 = col[idx + 0], j1 = col[idx + 1], j2 = col[idx + 2], j3 = col[idx + 3];
        int j4 = col[idx + 4], j5 = col[idx + 5], j6 = col[idx + 6], j7 = col[idx + 7];
        float4 v0 = *(const float4*)&G[j0 * D + c];
        float4 v1 = *(const float4*)&G[j1 * D + c];
        float4 v2 = *(const float4*)&G[j2 * D + c];
        float4 v3 = *(const float4*)&G[j3 * D + c];
        float4 v4 = *(const float4*)&G[j4 * D + c];
        float4 v5 = *(const float4*)&G[j5 * D + c];
        float4 v6 = *(const float4*)&G[j6 * D + c];
        float4 v7 = *(const float4*)&G[j7 * D + c];
        acc.x += ((v0.x + v1.x) + (v2.x + v3.x)) + ((v4.x + v5.x) + (v6.x + v7.x));
        acc.y += ((v0.y + v1.y) + (v2.y + v3.y)) + ((v4.y + v5.y) + (v6.y + v7.y));
        acc.z += ((v0.z + v1.z) + (v2.z + v3.z)) + ((v4.z + v5.z) + (v6.z + v7.z));
        acc.w += ((v0.w + v1.w) + (v2.w + v3.w)) + ((v4.w + v5.w) + (v6.w + v7.w));
    }
    for (; idx < e; ++idx) {
        int j = col[idx];
        float4 v = *(const float4*)&G[j * D + c];
        acc.x += v.x; acc.y += v.y; acc.z += v.z; acc.w += v.w;
    }

    float dv = dinv[node];
    float4 b = *(const float4*)&bias[c];
    float4 o;
    o.x = fmaxf(fmaf(dv, acc.x, b.x), 0.f);
    o.y = fmaxf(fmaf(dv, acc.y, b.y), 0.f);
    o.z = fmaxf(fmaf(dv, acc.z, b.z), 0.f);
    o.w = fmaxf(fmaf(dv, acc.w, b.w), 0.f);
    *(float4*)&out[node * D + c] = o;
}

// ----------------------------------------------------------------
extern "C" void kernel_launch(void* const* d_in, const int* in_sizes, int n_in,
                              void* d_out, int out_size, void* d_ws, size_t ws_size,
                              hipStream_t stream) {
    const float* x    = (const float*)d_in[0];
    const int*   edge = (const int*)d_in[1];
    const float* W0   = (const float*)d_in[2];
    const float* b0   = (const float*)d_in[3];
    const float* W1   = (const float*)d_in[4];
    const float* b1   = (const float*)d_in[5];
    float* out = (float*)d_out;

    const int N_ = in_sizes[0] / D;
    const int E_ = in_sizes[1] / 2;
    const int* srcp = edge;       // edge_index[0]
    const int* dstp = edge + E_;  // edge_index[1]

    char* p = (char*)d_ws;
    auto carve = [&](size_t bytes) { char* q = p; p += (bytes + 255) & ~(size_t)255; return q; };
    int*   cnt    = (int*)  carve((size_t)N_ * 4);
    int*   offs   = (int*)  carve((size_t)(N_ + 1) * 4);
    int*   bsum   = (int*)  carve(1024);
    float* dinv   = (float*)carve((size_t)N_ * 4);
    int*   rank   = (int*)  carve((size_t)E_ * 4);
    int*   col    = (int*)  carve((size_t)E_ * 4);
    float* g      = (float*)carve((size_t)N_ * D * 4);

    hipMemsetAsync(cnt, 0, (size_t)N_ * 4, stream);

    const int nb = (N_ + 255) / 256; // <=256 blocks required by scan2 (196 for N=50000)

    const bool vec_ok = ((E_ & 3) == 0) &&
                        ((((uintptr_t)srcp) & 15) == 0) && ((((uintptr_t)dstp) & 15) == 0);
    if (vec_ok) {
        const int n4 = E_ / 4;
        const int vb = (n4 + 255) / 256;
        count_rank_vec<<<vb, 256, 0, stream>>>(dstp, cnt, rank, n4, E_);
        scan1_kernel<<<nb, 256, 0, stream>>>(cnt, offs, bsum, N_);
        scan2_kernel<<<1, 256, 0, stream>>>(bsum, nb);
        finalize_kernel<<<nb, 256, 0, stream>>>(cnt, offs, dinv, bsum, N_, E_);
        fill_vec<<<vb, 256, 0, stream>>>(srcp, dstp, rank, offs, col, n4, E_);
    } else {
        const int eb = (E_ + 255) / 256;
        count_rank_scalar<<<eb, 256, 0, stream>>>(dstp, cnt, rank, E_);
        scan1_kernel<<<nb, 256, 0, stream>>>(cnt, offs, bsum, N_);
        scan2_kernel<<<1, 256, 0, stream>>>(bsum, nb);
        finalize_kernel<<<nb, 256, 0, stream>>>(cnt, offs, dinv, bsum, N_, E_);
        fill_scalar<<<eb, 256, 0, stream>>>(srcp, dstp, rank, offs, col, E_);
    }

    const int gb = (N_ + TILE_ROWS - 1) / TILE_ROWS;
    const int ab = (N_ + 7) / 8;

    gemm_scale_kernel<<<gb, 256, 0, stream>>>(x, W0, dinv, g, N_);
    aggregate_kernel<<<ab, 256, 0, stream>>>(g, offs, col, dinv, b0, out, N_);
    gemm_scale_kernel<<<gb, 256, 0, stream>>>(out, W1, dinv, g, N_);
    aggregate_kernel<<<ab, 256, 0, stream>>>(g, offs, col, dinv, b1, out, N_);
}

// Round 3
// 412.832 us; speedup vs baseline: 1.5034x; 1.3653x over previous
//
#include <hip/hip_runtime.h>
#include <hip/hip_bf16.h>

#define D 128
#define KT 32
#define TILE_ROWS 64

// fp32 -> bf16 round-to-nearest-even (bit pattern)
static __device__ inline unsigned int f2bf(float f) {
    unsigned int u = __float_as_uint(f);
    return (u + 0x7FFFu + ((u >> 16) & 1u)) >> 16;
}
// unpack 4 bf16 (as uint2) -> float4
static __device__ inline float4 bf4_to_f4(uint2 p) {
    float4 v;
    v.x = __uint_as_float(p.x << 16);
    v.y = __uint_as_float(p.x & 0xFFFF0000u);
    v.z = __uint_as_float(p.y << 16);
    v.w = __uint_as_float(p.y & 0xFFFF0000u);
    return v;
}

// ---------------------------------------------------------------- count + rank (vectorized)
__global__ __launch_bounds__(256) void count_rank_vec(const int* __restrict__ dst,
                                                      int* __restrict__ cnt,
                                                      int* __restrict__ rank,
                                                      int n4, int E_) {
    int i = blockIdx.x * 256 + threadIdx.x;
    if (i < n4) {
        int4 d = ((const int4*)dst)[i];
        int4 r;
        r.x = atomicAdd(&cnt[d.x], 1);
        r.y = atomicAdd(&cnt[d.y], 1);
        r.z = atomicAdd(&cnt[d.z], 1);
        r.w = atomicAdd(&cnt[d.w], 1);
        ((int4*)rank)[i] = r;
    }
    if (i == 0) {
        for (int e = n4 * 4; e < E_; ++e) rank[e] = atomicAdd(&cnt[dst[e]], 1);
    }
}

__global__ void count_rank_scalar(const int* __restrict__ dst, int* __restrict__ cnt,
                                  int* __restrict__ rank, int E_) {
    int e = blockIdx.x * blockDim.x + threadIdx.x;
    if (e < E_) rank[e] = atomicAdd(&cnt[dst[e]], 1);
}

// ---------------------------------------------------------------- block scan + block sums
__global__ __launch_bounds__(256) void scan1_kernel(const int* __restrict__ cnt,
                                                    int* __restrict__ offs,
                                                    int* __restrict__ bsum, int n) {
    __shared__ int s[256];
    int i = blockIdx.x * 256 + threadIdx.x;
    int v = (i < n) ? cnt[i] : 0;
    s[threadIdx.x] = v;
    __syncthreads();
    #pragma unroll
    for (int off = 1; off < 256; off <<= 1) {
        int x = (threadIdx.x >= off) ? s[threadIdx.x - off] : 0;
        __syncthreads();
        s[threadIdx.x] += x;
        __syncthreads();
    }
    if (i < n) offs[i] = s[threadIdx.x] - v;
    if (threadIdx.x == 255) bsum[blockIdx.x] = s[255];
}

__global__ __launch_bounds__(256) void scan2_kernel(int* __restrict__ bsum, int nb) {
    __shared__ int s[256];
    int v = (threadIdx.x < nb) ? bsum[threadIdx.x] : 0;
    s[threadIdx.x] = v;
    __syncthreads();
    #pragma unroll
    for (int off = 1; off < 256; off <<= 1) {
        int x = (threadIdx.x >= off) ? s[threadIdx.x - off] : 0;
        __syncthreads();
        s[threadIdx.x] += x;
        __syncthreads();
    }
    if (threadIdx.x < nb) bsum[threadIdx.x] = s[threadIdx.x] - v;
}

__global__ void finalize_kernel(const int* __restrict__ cnt, int* __restrict__ offs,
                                float* __restrict__ dinv,
                                const int* __restrict__ bsum, int n, int Etot) {
    int i = blockIdx.x * 256 + threadIdx.x;
    if (i < n) {
        offs[i] = offs[i] + bsum[blockIdx.x];
        dinv[i] = rsqrtf((float)(cnt[i] + 1));
    }
    if (i == 0) offs[n] = Etot;
}

// ---------------------------------------------------------------- CSR fill (atomicExch: no dirty-line migration)
__global__ __launch_bounds__(256) void fill_vec(const int* __restrict__ src,
                                                const int* __restrict__ dst,
                                                const int* __restrict__ rank,
                                                const int* __restrict__ offs,
                                                int* __restrict__ col, int n4, int E_) {
    int i = blockIdx.x * 256 + threadIdx.x;
    if (i < n4) {
        int4 d = ((const int4*)dst)[i];
        int4 s = ((const int4*)src)[i];
        int4 r = ((const int4*)rank)[i];
        atomicExch(&col[offs[d.x] + r.x], s.x);
        atomicExch(&col[offs[d.y] + r.y], s.y);
        atomicExch(&col[offs[d.z] + r.z], s.z);
        atomicExch(&col[offs[d.w] + r.w], s.w);
    }
    if (i == 0) {
        for (int e = n4 * 4; e < E_; ++e)
            atomicExch(&col[offs[dst[e]] + rank[e]], src[e]);
    }
}

__global__ void fill_scalar(const int* __restrict__ src, const int* __restrict__ dst,
                            const int* __restrict__ rank, const int* __restrict__ offs,
                            int* __restrict__ col, int E_) {
    int e = blockIdx.x * blockDim.x + threadIdx.x;
    if (e < E_) atomicExch(&col[offs[dst[e]] + rank[e]], src[e]);
}

// ---------------------------------------------------------------- G(bf16) = (A @ W) * dinv[row]
// Epilogue packs each thread's 4 fp32 cols into 4 bf16 (uint2, 8B store).
__global__ __launch_bounds__(256) void gemm_scale_kernel(const float* __restrict__ A,
                                                         const float* __restrict__ W,
                                                         const float* __restrict__ dinv,
                                                         uint2* __restrict__ Gb, int nrows) {
    __shared__ float As[TILE_ROWS][KT + 4];
    __shared__ float Ws[KT][D];

    const int tid = threadIdx.x;
    const int tc  = tid & 31;
    const int tr  = tid >> 5;
    const int row0 = blockIdx.x * TILE_ROWS;

    float acc[8][4];
    #pragma unroll
    for (int r = 0; r < 8; ++r)
        #pragma unroll
        for (int c = 0; c < 4; ++c) acc[r][c] = 0.f;

    for (int kc = 0; kc < D; kc += KT) {
        #pragma unroll
        for (int l = 0; l < 2; ++l) {
            int li = tid + l * 256;
            int r  = li >> 3;
            int k4 = li & 7;
            int grow = row0 + r;
            float4 v = make_float4(0.f, 0.f, 0.f, 0.f);
            if (grow < nrows) v = *(const float4*)&A[grow * D + kc + 4 * k4];
            *(float4*)&As[r][4 * k4] = v;
        }
        #pragma unroll
        for (int l = 0; l < 4; ++l) {
            int li = tid + l * 256;
            int k  = li >> 5;
            int c4 = li & 31;
            *(float4*)&Ws[k][4 * c4] = *(const float4*)&W[(kc + k) * D + 4 * c4];
        }
        __syncthreads();

        #pragma unroll
        for (int k4 = 0; k4 < KT / 4; ++k4) {
            float4 w0 = *(float4*)&Ws[4 * k4 + 0][4 * tc];
            float4 w1 = *(float4*)&Ws[4 * k4 + 1][4 * tc];
            float4 w2 = *(float4*)&Ws[4 * k4 + 2][4 * tc];
            float4 w3 = *(float4*)&Ws[4 * k4 + 3][4 * tc];
            #pragma unroll
            for (int r = 0; r < 8; ++r) {
                float4 a = *(float4*)&As[tr * 8 + r][4 * k4];
                acc[r][0] += a.x * w0.x + a.y * w1.x + a.z * w2.x + a.w * w3.x;
                acc[r][1] += a.x * w0.y + a.y * w1.y + a.z * w2.y + a.w * w3.y;
                acc[r][2] += a.x * w0.z + a.y * w1.z + a.z * w2.z + a.w * w3.z;
                acc[r][3] += a.x * w0.w + a.y * w1.w + a.z * w2.w + a.w * w3.w;
            }
        }
        __syncthreads();
    }

    #pragma unroll
    for (int r = 0; r < 8; ++r) {
        int grow = row0 + tr * 8 + r;
        if (grow < nrows) {
            float s = dinv[grow];
            uint2 o;
            o.x = f2bf(acc[r][0] * s) | (f2bf(acc[r][1] * s) << 16);
            o.y = f2bf(acc[r][2] * s) | (f2bf(acc[r][3] * s) << 16);
            Gb[grow * 32 + tc] = o; // 32 uint2 per 128-col row
        }
    }
}

// ---------------------------------------------------------------- out[i] = relu(dinv[i]*(sum_j g[j] + g[i]) + b)
// g rows are bf16 (256B); one 32-lane group per node, 8B (4 bf16)/lane.
__global__ __launch_bounds__(256) void aggregate_kernel(const uint2* __restrict__ Gb,
                                                        const int* __restrict__ offs,
                                                        const int* __restrict__ col,
                                                        const float* __restrict__ dinv,
                                                        const float* __restrict__ bias,
                                                        float* __restrict__ out, int nnodes) {
    const int lane = threadIdx.x & 31;
    const int node = blockIdx.x * 8 + (threadIdx.x >> 5);
    if (node >= nnodes) return;

    float4 acc = bf4_to_f4(Gb[node * 32 + lane]); // self-loop
    int s = offs[node];
    int e = offs[node + 1];

    int idx = s;
    for (; idx + 8 <= e; idx += 8) {
        int j0 = col[idx + 0], j1 = col[idx + 1], j2 = col[idx + 2], j3 = col[idx + 3];
        int j4 = col[idx + 4], j5 = col[idx + 5], j6 = col[idx + 6], j7 = col[idx + 7];
        uint2 p0 = Gb[j0 * 32 + lane];
        uint2 p1 = Gb[j1 * 32 + lane];
        uint2 p2 = Gb[j2 * 32 + lane];
        uint2 p3 = Gb[j3 * 32 + lane];
        uint2 p4 = Gb[j4 * 32 + lane];
        uint2 p5 = Gb[j5 * 32 + lane];
        uint2 p6 = Gb[j6 * 32 + lane];
        uint2 p7 = Gb[j7 * 32 + lane];
        float4 v0 = bf4_to_f4(p0), v1 = bf4_to_f4(p1), v2 = bf4_to_f4(p2), v3 = bf4_to_f4(p3);
        float4 v4 = bf4_to_f4(p4), v5 = bf4_to_f4(p5), v6 = bf4_to_f4(p6), v7 = bf4_to_f4(p7);
        acc.x += ((v0.x + v1.x) + (v2.x + v3.x)) + ((v4.x + v5.x) + (v6.x + v7.x));
        acc.y += ((v0.y + v1.y) + (v2.y + v3.y)) + ((v4.y + v5.y) + (v6.y + v7.y));
        acc.z += ((v0.z + v1.z) + (v2.z + v3.z)) + ((v4.z + v5.z) + (v6.z + v7.z));
        acc.w += ((v0.w + v1.w) + (v2.w + v3.w)) + ((v4.w + v5.w) + (v6.w + v7.w));
    }
    for (; idx < e; ++idx) {
        float4 v = bf4_to_f4(Gb[col[idx] * 32 + lane]);
        acc.x += v.x; acc.y += v.y; acc.z += v.z; acc.w += v.w;
    }

    float dv = dinv[node];
    float4 b = *(const float4*)&bias[lane * 4];
    float4 o;
    o.x = fmaxf(fmaf(dv, acc.x, b.x), 0.f);
    o.y = fmaxf(fmaf(dv, acc.y, b.y), 0.f);
    o.z = fmaxf(fmaf(dv, acc.z, b.z), 0.f);
    o.w = fmaxf(fmaf(dv, acc.w, b.w), 0.f);
    *(float4*)&out[node * D + lane * 4] = o;
}

// ----------------------------------------------------------------
extern "C" void kernel_launch(void* const* d_in, const int* in_sizes, int n_in,
                              void* d_out, int out_size, void* d_ws, size_t ws_size,
                              hipStream_t stream) {
    const float* x    = (const float*)d_in[0];
    const int*   edge = (const int*)d_in[1];
    const float* W0   = (const float*)d_in[2];
    const float* b0   = (const float*)d_in[3];
    const float* W1   = (const float*)d_in[4];
    const float* b1   = (const float*)d_in[5];
    float* out = (float*)d_out;

    const int N_ = in_sizes[0] / D;
    const int E_ = in_sizes[1] / 2;
    const int* srcp = edge;
    const int* dstp = edge + E_;

    char* p = (char*)d_ws;
    auto carve = [&](size_t bytes) { char* q = p; p += (bytes + 255) & ~(size_t)255; return q; };
    int*   cnt    = (int*)  carve((size_t)N_ * 4);
    int*   offs   = (int*)  carve((size_t)(N_ + 1) * 4);
    int*   bsum   = (int*)  carve(1024);
    float* dinv   = (float*)carve((size_t)N_ * 4);
    int*   rank   = (int*)  carve((size_t)E_ * 4);
    int*   col    = (int*)  carve((size_t)E_ * 4);
    uint2* gb     = (uint2*)carve((size_t)N_ * D * 2); // bf16 g

    hipMemsetAsync(cnt, 0, (size_t)N_ * 4, stream);

    const int nb = (N_ + 255) / 256;

    const bool vec_ok = ((E_ & 3) == 0) &&
                        ((((uintptr_t)srcp) & 15) == 0) && ((((uintptr_t)dstp) & 15) == 0);
    if (vec_ok) {
        const int n4 = E_ / 4;
        const int vb = (n4 + 255) / 256;
        count_rank_vec<<<vb, 256, 0, stream>>>(dstp, cnt, rank, n4, E_);
        scan1_kernel<<<nb, 256, 0, stream>>>(cnt, offs, bsum, N_);
        scan2_kernel<<<1, 256, 0, stream>>>(bsum, nb);
        finalize_kernel<<<nb, 256, 0, stream>>>(cnt, offs, dinv, bsum, N_, E_);
        fill_vec<<<vb, 256, 0, stream>>>(srcp, dstp, rank, offs, col, n4, E_);
    } else {
        const int eb = (E_ + 255) / 256;
        count_rank_scalar<<<eb, 256, 0, stream>>>(dstp, cnt, rank, E_);
        scan1_kernel<<<nb, 256, 0, stream>>>(cnt, offs, bsum, N_);
        scan2_kernel<<<1, 256, 0, stream>>>(bsum, nb);
        finalize_kernel<<<nb, 256, 0, stream>>>(cnt, offs, dinv, bsum, N_, E_);
        fill_scalar<<<eb, 256, 0, stream>>>(srcp, dstp, rank, offs, col, E_);
    }

    const int gb_blocks = (N_ + TILE_ROWS - 1) / TILE_ROWS;
    const int ab = (N_ + 7) / 8;

    gemm_scale_kernel<<<gb_blocks, 256, 0, stream>>>(x, W0, dinv, gb, N_);
    aggregate_kernel<<<ab, 256, 0, stream>>>(gb, offs, col, dinv, b0, out, N_);
    gemm_scale_kernel<<<gb_blocks, 256, 0, stream>>>(out, W1, dinv, gb, N_);
    aggregate_kernel<<<ab, 256, 0, stream>>>(gb, offs, col, dinv, b1, out, N_);
}

// Round 4
// 324.718 us; speedup vs baseline: 1.9114x; 1.2714x over previous
//
#include <hip/hip_runtime.h>
#include <hip/hip_bf16.h>

#define D 128
#define KT 32
#define TILE_ROWS 64
#define CHUNK 8192   // edges per build block

// NOTE: this build path packs (dst&255, src) into one uint -> requires N <= 65536.
// Problem shape is fixed at N=50000.

// fp32 -> bf16 round-to-nearest-even (bit pattern)
static __device__ inline unsigned int f2bf(float f) {
    unsigned int u = __float_as_uint(f);
    return (u + 0x7FFFu + ((u >> 16) & 1u)) >> 16;
}
static __device__ inline float4 bf4_to_f4(uint2 p) {
    float4 v;
    v.x = __uint_as_float(p.x << 16);
    v.y = __uint_as_float(p.x & 0xFFFF0000u);
    v.z = __uint_as_float(p.y << 16);
    v.w = __uint_as_float(p.y & 0xFFFF0000u);
    return v;
}

// ---------------------------------------------------------------- K1: per-chunk bucket histogram (LDS only)
__global__ __launch_bounds__(256) void k1_hist(const int* __restrict__ dst,
                                               int* __restrict__ blockhist, int E_) {
    __shared__ int h[256];
    const int b = blockIdx.x, tid = threadIdx.x;
    h[tid] = 0;
    __syncthreads();
    const int e0 = b * CHUNK;
    const int e1 = min(E_, e0 + CHUNK);
    for (int e = e0 + tid; e < e1; e += 256)
        atomicAdd(&h[dst[e] >> 8], 1);
    __syncthreads();
    blockhist[b * 256 + tid] = h[tid];
}

// ---------------------------------------------------------------- K2: redundant full-table scan per block (no serial chain)
// gbase[b][beta] = bucket_start[beta] + sum_{b'<b} blockhist[b'][beta]
__global__ __launch_bounds__(256) void k2_scan(const int* __restrict__ blockhist,
                                               int* __restrict__ gbase,
                                               int* __restrict__ bucket_offs,
                                               int NB, int NBUK, int E_) {
    __shared__ int s[256];
    const int myb = blockIdx.x, tid = threadIdx.x;
    int total = 0, prefix = 0;
    #pragma unroll 4
    for (int b2 = 0; b2 < NB; ++b2) {
        int t = blockhist[b2 * 256 + tid];
        total += t;
        prefix += (b2 < myb) ? t : 0;
    }
    // exclusive scan of per-bucket totals over 256 threads
    s[tid] = total;
    __syncthreads();
    #pragma unroll
    for (int off = 1; off < 256; off <<= 1) {
        int x = (tid >= off) ? s[tid - off] : 0;
        __syncthreads();
        s[tid] += x;
        __syncthreads();
    }
    int bstart = s[tid] - total; // exclusive
    gbase[myb * 256 + tid] = bstart + prefix;
    if (myb == 0) {
        if (tid < NBUK) bucket_offs[tid] = bstart;
        if (tid == 0) bucket_offs[NBUK] = E_;
    }
}

// ---------------------------------------------------------------- K3: scatter packed (vlow,src) into bucket-major staging
__global__ __launch_bounds__(256) void k3_scatter(const int* __restrict__ dst,
                                                  const int* __restrict__ src,
                                                  const int* __restrict__ gbase,
                                                  unsigned int* __restrict__ buf, int E_) {
    __shared__ int c[256];
    const int b = blockIdx.x, tid = threadIdx.x;
    c[tid] = gbase[b * 256 + tid];
    __syncthreads();
    const int e0 = b * CHUNK;
    const int e1 = min(E_, e0 + CHUNK);
    for (int e = e0 + tid; e < e1; e += 256) {
        int v = dst[e];
        int sdx = src[e];
        int pos = atomicAdd(&c[v >> 8], 1);
        buf[pos] = (unsigned int)sdx | ((unsigned int)(v & 255) << 16);
    }
}

// ---------------------------------------------------------------- K4: per-bucket counting sort -> col, offs, dinv
__global__ __launch_bounds__(256) void k4_bucket(const unsigned int* __restrict__ buf,
                                                 const int* __restrict__ bucket_offs,
                                                 int* __restrict__ offs,
                                                 float* __restrict__ dinv,
                                                 int* __restrict__ col, int N_, int E_) {
    __shared__ int h[256];
    __shared__ int s[256];
    __shared__ int c[256];
    const int beta = blockIdx.x, tid = threadIdx.x;
    const int start = bucket_offs[beta];
    const int end   = bucket_offs[beta + 1];

    h[tid] = 0;
    __syncthreads();
    for (int e = start + tid; e < end; e += 256)
        atomicAdd(&h[(buf[e] >> 16) & 255], 1);
    __syncthreads();

    int deg = h[tid];
    s[tid] = deg;
    __syncthreads();
    #pragma unroll
    for (int off = 1; off < 256; off <<= 1) {
        int x = (tid >= off) ? s[tid - off] : 0;
        __syncthreads();
        s[tid] += x;
        __syncthreads();
    }
    int excl = s[tid] - deg;

    int v0 = beta * 256 + tid;
    if (v0 < N_) {
        offs[v0] = start + excl;
        dinv[v0] = rsqrtf((float)(deg + 1));
    }
    if (beta == 0 && tid == 0) offs[N_] = E_;
    c[tid] = start + excl;
    __syncthreads();

    for (int e = start + tid; e < end; e += 256) {
        unsigned int p = buf[e];
        int pos = atomicAdd(&c[(p >> 16) & 255], 1);
        col[pos] = (int)(p & 0xFFFFu);
    }
}

// ---------------------------------------------------------------- G(bf16) = (A @ W) * dinv[row]
__global__ __launch_bounds__(256) void gemm_scale_kernel(const float* __restrict__ A,
                                                         const float* __restrict__ W,
                                                         const float* __restrict__ dinv,
                                                         uint2* __restrict__ Gb, int nrows) {
    __shared__ float As[TILE_ROWS][KT + 4];
    __shared__ float Ws[KT][D];

    const int tid = threadIdx.x;
    const int tc  = tid & 31;
    const int tr  = tid >> 5;
    const int row0 = blockIdx.x * TILE_ROWS;

    float acc[8][4];
    #pragma unroll
    for (int r = 0; r < 8; ++r)
        #pragma unroll
        for (int cc = 0; cc < 4; ++cc) acc[r][cc] = 0.f;

    for (int kc = 0; kc < D; kc += KT) {
        #pragma unroll
        for (int l = 0; l < 2; ++l) {
            int li = tid + l * 256;
            int r  = li >> 3;
            int k4 = li & 7;
            int grow = row0 + r;
            float4 v = make_float4(0.f, 0.f, 0.f, 0.f);
            if (grow < nrows) v = *(const float4*)&A[grow * D + kc + 4 * k4];
            *(float4*)&As[r][4 * k4] = v;
        }
        #pragma unroll
        for (int l = 0; l < 4; ++l) {
            int li = tid + l * 256;
            int k  = li >> 5;
            int c4 = li & 31;
            *(float4*)&Ws[k][4 * c4] = *(const float4*)&W[(kc + k) * D + 4 * c4];
        }
        __syncthreads();

        #pragma unroll
        for (int k4 = 0; k4 < KT / 4; ++k4) {
            float4 w0 = *(float4*)&Ws[4 * k4 + 0][4 * tc];
            float4 w1 = *(float4*)&Ws[4 * k4 + 1][4 * tc];
            float4 w2 = *(float4*)&Ws[4 * k4 + 2][4 * tc];
            float4 w3 = *(float4*)&Ws[4 * k4 + 3][4 * tc];
            #pragma unroll
            for (int r = 0; r < 8; ++r) {
                float4 a = *(float4*)&As[tr * 8 + r][4 * k4];
                acc[r][0] += a.x * w0.x + a.y * w1.x + a.z * w2.x + a.w * w3.x;
                acc[r][1] += a.x * w0.y + a.y * w1.y + a.z * w2.y + a.w * w3.y;
                acc[r][2] += a.x * w0.z + a.y * w1.z + a.z * w2.z + a.w * w3.z;
                acc[r][3] += a.x * w0.w + a.y * w1.w + a.z * w2.w + a.w * w3.w;
            }
        }
        __syncthreads();
    }

    #pragma unroll
    for (int r = 0; r < 8; ++r) {
        int grow = row0 + tr * 8 + r;
        if (grow < nrows) {
            float s = dinv[grow];
            uint2 o;
            o.x = f2bf(acc[r][0] * s) | (f2bf(acc[r][1] * s) << 16);
            o.y = f2bf(acc[r][2] * s) | (f2bf(acc[r][3] * s) << 16);
            Gb[grow * 32 + tc] = o;
        }
    }
}

// ---------------------------------------------------------------- out[i] = relu(dinv[i]*(sum_j g[j] + g[i]) + b)
__global__ __launch_bounds__(256) void aggregate_kernel(const uint2* __restrict__ Gb,
                                                        const int* __restrict__ offs,
                                                        const int* __restrict__ col,
                                                        const float* __restrict__ dinv,
                                                        const float* __restrict__ bias,
                                                        float* __restrict__ out, int nnodes) {
    const int lane = threadIdx.x & 31;
    const int node = blockIdx.x * 8 + (threadIdx.x >> 5);
    if (node >= nnodes) return;

    float4 acc = bf4_to_f4(Gb[node * 32 + lane]); // self-loop
    int s = offs[node];
    int e = offs[node + 1];

    int idx = s;
    for (; idx + 8 <= e; idx += 8) {
        int j0 = col[idx + 0], j1 = col[idx + 1], j2 = col[idx + 2], j3 = col[idx + 3];
        int j4 = col[idx + 4], j5 = col[idx + 5], j6 = col[idx + 6], j7 = col[idx + 7];
        uint2 p0 = Gb[j0 * 32 + lane];
        uint2 p1 = Gb[j1 * 32 + lane];
        uint2 p2 = Gb[j2 * 32 + lane];
        uint2 p3 = Gb[j3 * 32 + lane];
        uint2 p4 = Gb[j4 * 32 + lane];
        uint2 p5 = Gb[j5 * 32 + lane];
        uint2 p6 = Gb[j6 * 32 + lane];
        uint2 p7 = Gb[j7 * 32 + lane];
        float4 v0 = bf4_to_f4(p0), v1 = bf4_to_f4(p1), v2 = bf4_to_f4(p2), v3 = bf4_to_f4(p3);
        float4 v4 = bf4_to_f4(p4), v5 = bf4_to_f4(p5), v6 = bf4_to_f4(p6), v7 = bf4_to_f4(p7);
        acc.x += ((v0.x + v1.x) + (v2.x + v3.x)) + ((v4.x + v5.x) + (v6.x + v7.x));
        acc.y += ((v0.y + v1.y) + (v2.y + v3.y)) + ((v4.y + v5.y) + (v6.y + v7.y));
        acc.z += ((v0.z + v1.z) + (v2.z + v3.z)) + ((v4.z + v5.z) + (v6.z + v7.z));
        acc.w += ((v0.w + v1.w) + (v2.w + v3.w)) + ((v4.w + v5.w) + (v6.w + v7.w));
    }
    for (; idx < e; ++idx) {
        float4 v = bf4_to_f4(Gb[col[idx] * 32 + lane]);
        acc.x += v.x; acc.y += v.y; acc.z += v.z; acc.w += v.w;
    }

    float dv = dinv[node];
    float4 b = *(const float4*)&bias[lane * 4];
    float4 o;
    o.x = fmaxf(fmaf(dv, acc.x, b.x), 0.f);
    o.y = fmaxf(fmaf(dv, acc.y, b.y), 0.f);
    o.z = fmaxf(fmaf(dv, acc.z, b.z), 0.f);
    o.w = fmaxf(fmaf(dv, acc.w, b.w), 0.f);
    *(float4*)&out[node * D + lane * 4] = o;
}

// ----------------------------------------------------------------
extern "C" void kernel_launch(void* const* d_in, const int* in_sizes, int n_in,
                              void* d_out, int out_size, void* d_ws, size_t ws_size,
                              hipStream_t stream) {
    const float* x    = (const float*)d_in[0];
    const int*   edge = (const int*)d_in[1];
    const float* W0   = (const float*)d_in[2];
    const float* b0   = (const float*)d_in[3];
    const float* W1   = (const float*)d_in[4];
    const float* b1   = (const float*)d_in[5];
    float* out = (float*)d_out;

    const int N_ = in_sizes[0] / D;
    const int E_ = in_sizes[1] / 2;
    const int* srcp = edge;       // edge_index[0]
    const int* dstp = edge + E_;  // edge_index[1]

    const int NB   = (E_ + CHUNK - 1) / CHUNK;  // 196 edge chunks
    const int NBUK = (N_ + 255) >> 8;           // 196 node buckets (<=256 for N<=65536)

    char* p = (char*)d_ws;
    auto carve = [&](size_t bytes) { char* q = p; p += (bytes + 255) & ~(size_t)255; return q; };
    int*          blockhist = (int*)          carve((size_t)NB * 256 * 4);
    int*          gbase     = (int*)          carve((size_t)NB * 256 * 4);
    int*          buck_offs = (int*)          carve((size_t)(NBUK + 1) * 4);
    int*          offs      = (int*)          carve((size_t)(N_ + 1) * 4);
    float*        dinv      = (float*)        carve((size_t)N_ * 4);
    unsigned int* buf       = (unsigned int*) carve((size_t)E_ * 4);
    int*          col       = (int*)          carve((size_t)E_ * 4);
    uint2*        gb        = (uint2*)        carve((size_t)N_ * D * 2);

    k1_hist   <<<NB,   256, 0, stream>>>(dstp, blockhist, E_);
    k2_scan   <<<NB,   256, 0, stream>>>(blockhist, gbase, buck_offs, NB, NBUK, E_);
    k3_scatter<<<NB,   256, 0, stream>>>(dstp, srcp, gbase, buf, E_);
    k4_bucket <<<NBUK, 256, 0, stream>>>(buf, buck_offs, offs, dinv, col, N_, E_);

    const int gb_blocks = (N_ + TILE_ROWS - 1) / TILE_ROWS;
    const int ab = (N_ + 7) / 8;

    gemm_scale_kernel<<<gb_blocks, 256, 0, stream>>>(x, W0, dinv, gb, N_);
    aggregate_kernel <<<ab,        256, 0, stream>>>(gb, offs, col, dinv, b0, out, N_);
    gemm_scale_kernel<<<gb_blocks, 256, 0, stream>>>(out, W1, dinv, gb, N_);
    aggregate_kernel <<<ab,        256, 0, stream>>>(gb, offs, col, dinv, b1, out, N_);
}

// Round 5
// 282.696 us; speedup vs baseline: 2.1955x; 1.1486x over previous
//
#include <hip/hip_runtime.h>
#include <hip/hip_bf16.h>

#define D 128
#define CHUNK 8192   // edges per build block

// NOTE: build path packs (dst&255, src) into one uint -> requires N <= 65536.

typedef __attribute__((ext_vector_type(8))) short short8;
typedef __attribute__((ext_vector_type(4))) float floatx4;

// fp32 -> bf16 round-to-nearest-even (bit pattern)
static __device__ inline unsigned int f2bf(float f) {
    unsigned int u = __float_as_uint(f);
    return (u + 0x7FFFu + ((u >> 16) & 1u)) >> 16;
}
static __device__ inline float4 bf4_to_f4(uint2 p) {
    float4 v;
    v.x = __uint_as_float(p.x << 16);
    v.y = __uint_as_float(p.x & 0xFFFF0000u);
    v.z = __uint_as_float(p.y << 16);
    v.w = __uint_as_float(p.y & 0xFFFF0000u);
    return v;
}

// ---------------------------------------------------------------- K0: swizzle W0/W1 into MFMA B-fragment order, hi/lo bf16 split
// B frag for (tile t, kchunk q, lane): 8 bf16 at k = q*32 + (lane>>4)*8 + j, n = t*16 + (lane&15)
__global__ __launch_bounds__(256) void k0_swizzle(const float* __restrict__ W0,
                                                  const float* __restrict__ W1,
                                                  short8* __restrict__ whi0, short8* __restrict__ wlo0,
                                                  short8* __restrict__ whi1, short8* __restrict__ wlo1) {
    int gid = blockIdx.x * 256 + threadIdx.x; // 0..4095
    const float* W = (gid < 2048) ? W0 : W1;
    short8* whi = (gid < 2048) ? whi0 : whi1;
    short8* wlo = (gid < 2048) ? wlo0 : wlo1;
    int tid = gid & 2047;
    int t = tid >> 8, q = (tid >> 6) & 3, lane = tid & 63;
    short8 hi, lo;
    #pragma unroll
    for (int j = 0; j < 8; ++j) {
        int k = q * 32 + (lane >> 4) * 8 + j;
        int n = t * 16 + (lane & 15);
        float w = W[k * D + n];
        unsigned int h = f2bf(w);
        hi[j] = (short)h;
        lo[j] = (short)f2bf(w - __uint_as_float(h << 16));
    }
    whi[tid] = hi;
    wlo[tid] = lo;
}

// ---------------------------------------------------------------- K1: per-chunk bucket histogram (LDS only)
__global__ __launch_bounds__(256) void k1_hist(const int* __restrict__ dst,
                                               int* __restrict__ blockhist, int E_) {
    __shared__ int h[256];
    const int b = blockIdx.x, tid = threadIdx.x;
    h[tid] = 0;
    __syncthreads();
    const int e0 = b * CHUNK;
    const int e1 = min(E_, e0 + CHUNK);
    for (int e = e0 + tid; e < e1; e += 256)
        atomicAdd(&h[dst[e] >> 8], 1);
    __syncthreads();
    blockhist[b * 256 + tid] = h[tid];
}

// ---------------------------------------------------------------- K2: redundant full-table scan per block
__global__ __launch_bounds__(256) void k2_scan(const int* __restrict__ blockhist,
                                               int* __restrict__ gbase,
                                               int* __restrict__ bucket_offs,
                                               int NB, int NBUK, int E_) {
    __shared__ int s[256];
    const int myb = blockIdx.x, tid = threadIdx.x;
    int total = 0, prefix = 0;
    #pragma unroll 4
    for (int b2 = 0; b2 < NB; ++b2) {
        int t = blockhist[b2 * 256 + tid];
        total += t;
        prefix += (b2 < myb) ? t : 0;
    }
    s[tid] = total;
    __syncthreads();
    #pragma unroll
    for (int off = 1; off < 256; off <<= 1) {
        int x = (tid >= off) ? s[tid - off] : 0;
        __syncthreads();
        s[tid] += x;
        __syncthreads();
    }
    int bstart = s[tid] - total; // exclusive
    gbase[myb * 256 + tid] = bstart + prefix;
    if (myb == 0) {
        if (tid < NBUK) bucket_offs[tid] = bstart;
        if (tid == 0) bucket_offs[NBUK] = E_;
    }
}

// ---------------------------------------------------------------- K3: scatter packed (vlow,src) into bucket-major staging
__global__ __launch_bounds__(256) void k3_scatter(const int* __restrict__ dst,
                                                  const int* __restrict__ src,
                                                  const int* __restrict__ gbase,
                                                  unsigned int* __restrict__ buf, int E_) {
    __shared__ int c[256];
    const int b = blockIdx.x, tid = threadIdx.x;
    c[tid] = gbase[b * 256 + tid];
    __syncthreads();
    const int e0 = b * CHUNK;
    const int e1 = min(E_, e0 + CHUNK);
    for (int e = e0 + tid; e < e1; e += 256) {
        int v = dst[e];
        int sdx = src[e];
        int pos = atomicAdd(&c[v >> 8], 1);
        buf[pos] = (unsigned int)sdx | ((unsigned int)(v & 255) << 16);
    }
}

// ---------------------------------------------------------------- K4: per-bucket counting sort -> col, offs, dinv
__global__ __launch_bounds__(256) void k4_bucket(const unsigned int* __restrict__ buf,
                                                 const int* __restrict__ bucket_offs,
                                                 int* __restrict__ offs,
                                                 float* __restrict__ dinv,
                                                 int* __restrict__ col, int N_, int E_) {
    __shared__ int h[256];
    __shared__ int s[256];
    __shared__ int c[256];
    const int beta = blockIdx.x, tid = threadIdx.x;
    const int start = bucket_offs[beta];
    const int end   = bucket_offs[beta + 1];

    h[tid] = 0;
    __syncthreads();
    for (int e = start + tid; e < end; e += 256)
        atomicAdd(&h[(buf[e] >> 16) & 255], 1);
    __syncthreads();

    int deg = h[tid];
    s[tid] = deg;
    __syncthreads();
    #pragma unroll
    for (int off = 1; off < 256; off <<= 1) {
        int x = (tid >= off) ? s[tid - off] : 0;
        __syncthreads();
        s[tid] += x;
        __syncthreads();
    }
    int excl = s[tid] - deg;

    int v0 = beta * 256 + tid;
    if (v0 < N_) {
        offs[v0] = start + excl;
        dinv[v0] = rsqrtf((float)(deg + 1));
    }
    if (beta == 0 && tid == 0) offs[N_] = E_;
    c[tid] = start + excl;
    __syncthreads();

    for (int e = start + tid; e < end; e += 256) {
        unsigned int p = buf[e];
        int pos = atomicAdd(&c[(p >> 16) & 255], 1);
        col[pos] = (int)(p & 0xFFFFu);
    }
}

// ---------------------------------------------------------------- MFMA GEMM: Gb(bf16) = (A @ W) * dinv[row]
// Split-bf16 3-term: A*W = ahi*whi + alo*whi + ahi*wlo (err ~2^-16 rel).
// 64 rows/block, 4 waves, each wave one 16-row stripe x all 8 n-tiles.
__global__ __launch_bounds__(256) void gemm_mfma(const float* __restrict__ A,
                                                 const short8* __restrict__ whi,
                                                 const short8* __restrict__ wlo,
                                                 const float* __restrict__ dinv,
                                                 uint2* __restrict__ Gb, int nrows) {
    __shared__ float tileT[128][65]; // [col][row] col-major; write banks 2-way max

    const int tid  = threadIdx.x;
    const int wave = tid >> 6, lane = tid & 63;
    const int m = lane & 15, quad = lane >> 4;
    const int rowInBlk = wave * 16;
    const int arow = min(blockIdx.x * 64 + rowInBlk + m, nrows - 1);
    const float* Ap = A + (size_t)arow * D + quad * 8;

    floatx4 acc[8];
    #pragma unroll
    for (int t = 0; t < 8; ++t) acc[t] = (floatx4){0.f, 0.f, 0.f, 0.f};

    #pragma unroll
    for (int q = 0; q < 4; ++q) {
        float4 a0 = *(const float4*)(Ap + q * 32);
        float4 a1 = *(const float4*)(Ap + q * 32 + 4);
        float av[8] = {a0.x, a0.y, a0.z, a0.w, a1.x, a1.y, a1.z, a1.w};
        short8 ahi, alo;
        #pragma unroll
        for (int j = 0; j < 8; ++j) {
            unsigned int h = f2bf(av[j]);
            ahi[j] = (short)h;
            alo[j] = (short)f2bf(av[j] - __uint_as_float(h << 16));
        }
        #pragma unroll
        for (int t = 0; t < 8; ++t) {
            short8 bh = whi[(t * 4 + q) * 64 + lane];
            short8 bl = wlo[(t * 4 + q) * 64 + lane];
            acc[t] = __builtin_amdgcn_mfma_f32_16x16x32_bf16(ahi, bh, acc[t], 0, 0, 0);
            acc[t] = __builtin_amdgcn_mfma_f32_16x16x32_bf16(alo, bh, acc[t], 0, 0, 0);
            acc[t] = __builtin_amdgcn_mfma_f32_16x16x32_bf16(ahi, bl, acc[t], 0, 0, 0);
        }
    }

    // C/D layout: col = lane&15, row = quad*4 + reg  -> write transposed into LDS
    #pragma unroll
    for (int t = 0; t < 8; ++t)
        #pragma unroll
        for (int r = 0; r < 4; ++r)
            tileT[t * 16 + m][rowInBlk + quad * 4 + r] = acc[t][r];
    __syncthreads();

    // epilogue: row-major, scale by dinv, pack bf16, coalesced uint4 stores
    const int orow = tid >> 2, seg = tid & 3;
    const int grow = blockIdx.x * 64 + orow;
    if (grow < nrows) {
        float s = dinv[grow];
        #pragma unroll
        for (int i = 0; i < 4; ++i) {
            int c = seg * 32 + i * 8;
            float v0 = tileT[c + 0][orow] * s, v1 = tileT[c + 1][orow] * s;
            float v2 = tileT[c + 2][orow] * s, v3 = tileT[c + 3][orow] * s;
            float v4 = tileT[c + 4][orow] * s, v5 = tileT[c + 5][orow] * s;
            float v6 = tileT[c + 6][orow] * s, v7 = tileT[c + 7][orow] * s;
            uint4 o4;
            o4.x = f2bf(v0) | (f2bf(v1) << 16);
            o4.y = f2bf(v2) | (f2bf(v3) << 16);
            o4.z = f2bf(v4) | (f2bf(v5) << 16);
            o4.w = f2bf(v6) | (f2bf(v7) << 16);
            *(uint4*)&Gb[(size_t)grow * 32 + seg * 8 + i * 2] = o4;
        }
    }
}

// ---------------------------------------------------------------- out[i] = relu(dinv[i]*(sum_j g[j] + g[i]) + b)
// 16-deep gather batches for MLP (testing latency-bound hypothesis).
__global__ __launch_bounds__(256) void aggregate_kernel(const uint2* __restrict__ Gb,
                                                        const int* __restrict__ offs,
                                                        const int* __restrict__ col,
                                                        const float* __restrict__ dinv,
                                                        const float* __restrict__ bias,
                                                        float* __restrict__ out, int nnodes) {
    const int lane = threadIdx.x & 31;
    const int node = blockIdx.x * 8 + (threadIdx.x >> 5);
    if (node >= nnodes) return;

    float4 acc = bf4_to_f4(Gb[(size_t)node * 32 + lane]); // self-loop
    int s = offs[node];
    int e = offs[node + 1];

    int idx = s;
    for (; idx + 16 <= e; idx += 16) {
        int j[16];
        #pragma unroll
        for (int u = 0; u < 16; ++u) j[u] = col[idx + u];
        uint2 p[16];
        #pragma unroll
        for (int u = 0; u < 16; ++u) p[u] = Gb[(size_t)j[u] * 32 + lane];
        float4 t0 = make_float4(0.f, 0.f, 0.f, 0.f);
        float4 t1 = make_float4(0.f, 0.f, 0.f, 0.f);
        #pragma unroll
        for (int u = 0; u < 16; u += 2) {
            float4 v0 = bf4_to_f4(p[u]);
            float4 v1 = bf4_to_f4(p[u + 1]);
            t0.x += v0.x; t0.y += v0.y; t0.z += v0.z; t0.w += v0.w;
            t1.x += v1.x; t1.y += v1.y; t1.z += v1.z; t1.w += v1.w;
        }
        acc.x += t0.x + t1.x; acc.y += t0.y + t1.y;
        acc.z += t0.z + t1.z; acc.w += t0.w + t1.w;
    }
    for (; idx + 4 <= e; idx += 4) {
        int j0 = col[idx + 0], j1 = col[idx + 1], j2 = col[idx + 2], j3 = col[idx + 3];
        float4 v0 = bf4_to_f4(Gb[(size_t)j0 * 32 + lane]);
        float4 v1 = bf4_to_f4(Gb[(size_t)j1 * 32 + lane]);
        float4 v2 = bf4_to_f4(Gb[(size_t)j2 * 32 + lane]);
        float4 v3 = bf4_to_f4(Gb[(size_t)j3 * 32 + lane]);
        acc.x += (v0.x + v1.x) + (v2.x + v3.x);
        acc.y += (v0.y + v1.y) + (v2.y + v3.y);
        acc.z += (v0.z + v1.z) + (v2.z + v3.z);
        acc.w += (v0.w + v1.w) + (v2.w + v3.w);
    }
    for (; idx < e; ++idx) {
        float4 v = bf4_to_f4(Gb[(size_t)col[idx] * 32 + lane]);
        acc.x += v.x; acc.y += v.y; acc.z += v.z; acc.w += v.w;
    }

    float dv = dinv[node];
    float4 b = *(const float4*)&bias[lane * 4];
    float4 o;
    o.x = fmaxf(fmaf(dv, acc.x, b.x), 0.f);
    o.y = fmaxf(fmaf(dv, acc.y, b.y), 0.f);
    o.z = fmaxf(fmaf(dv, acc.z, b.z), 0.f);
    o.w = fmaxf(fmaf(dv, acc.w, b.w), 0.f);
    *(float4*)&out[node * D + lane * 4] = o;
}

// ----------------------------------------------------------------
extern "C" void kernel_launch(void* const* d_in, const int* in_sizes, int n_in,
                              void* d_out, int out_size, void* d_ws, size_t ws_size,
                              hipStream_t stream) {
    const float* x    = (const float*)d_in[0];
    const int*   edge = (const int*)d_in[1];
    const float* W0   = (const float*)d_in[2];
    const float* b0   = (const float*)d_in[3];
    const float* W1   = (const float*)d_in[4];
    const float* b1   = (const float*)d_in[5];
    float* out = (float*)d_out;

    const int N_ = in_sizes[0] / D;
    const int E_ = in_sizes[1] / 2;
    const int* srcp = edge;       // edge_index[0]
    const int* dstp = edge + E_;  // edge_index[1]

    const int NB   = (E_ + CHUNK - 1) / CHUNK;
    const int NBUK = (N_ + 255) >> 8;

    char* p = (char*)d_ws;
    auto carve = [&](size_t bytes) { char* q = p; p += (bytes + 255) & ~(size_t)255; return q; };
    int*          blockhist = (int*)          carve((size_t)NB * 256 * 4);
    int*          gbase     = (int*)          carve((size_t)NB * 256 * 4);
    int*          buck_offs = (int*)          carve((size_t)(NBUK + 1) * 4);
    int*          offs      = (int*)          carve((size_t)(N_ + 1) * 4);
    float*        dinv      = (float*)        carve((size_t)N_ * 4);
    unsigned int* buf       = (unsigned int*) carve((size_t)E_ * 4);
    int*          col       = (int*)          carve((size_t)E_ * 4);
    uint2*        gb        = (uint2*)        carve((size_t)N_ * D * 2);
    short8*       whi0      = (short8*)       carve(2048 * 16);
    short8*       wlo0      = (short8*)       carve(2048 * 16);
    short8*       whi1      = (short8*)       carve(2048 * 16);
    short8*       wlo1      = (short8*)       carve(2048 * 16);

    k0_swizzle<<<16,   256, 0, stream>>>(W0, W1, whi0, wlo0, whi1, wlo1);
    k1_hist   <<<NB,   256, 0, stream>>>(dstp, blockhist, E_);
    k2_scan   <<<NB,   256, 0, stream>>>(blockhist, gbase, buck_offs, NB, NBUK, E_);
    k3_scatter<<<NB,   256, 0, stream>>>(dstp, srcp, gbase, buf, E_);
    k4_bucket <<<NBUK, 256, 0, stream>>>(buf, buck_offs, offs, dinv, col, N_, E_);

    const int gmb = (N_ + 63) / 64;
    const int ab  = (N_ + 7) / 8;

    gemm_mfma       <<<gmb, 256, 0, stream>>>(x, whi0, wlo0, dinv, gb, N_);
    aggregate_kernel<<<ab,  256, 0, stream>>>(gb, offs, col, dinv, b0, out, N_);
    gemm_mfma       <<<gmb, 256, 0, stream>>>(out, whi1, wlo1, dinv, gb, N_);
    aggregate_kernel<<<ab,  256, 0, stream>>>(gb, offs, col, dinv, b1, out, N_);
}